// Round 5
// baseline (360.684 us; speedup 1.0000x reference)
//
#include <hip/hip_runtime.h>
#include <hip/hip_bf16.h>
#include <stdint.h>

#define B_ 4
#define T_ 2048
#define D_ 1024
#define H_ 16
#define HD_ 64
#define NKT (T_ / 64)

typedef __bf16 bf16;
typedef __bf16 bf16x8 __attribute__((ext_vector_type(8)));
typedef __bf16 bf16x4 __attribute__((ext_vector_type(4)));
typedef float f32x4 __attribute__((ext_vector_type(4)));
typedef uint32_t u32x4 __attribute__((ext_vector_type(4)));
typedef uint32_t u32x2 __attribute__((ext_vector_type(2)));

// 0.125 (1/sqrt(64)) * log2(e): folded into Q projection so attn uses native exp2
#define QSCALE 0.18033688011112042f

__device__ __forceinline__ float fast_exp2(float x) {
#if __has_builtin(__builtin_amdgcn_exp2f)
    return __builtin_amdgcn_exp2f(x);
#else
    return exp2f(x);
#endif
}

// async global->LDS, 16B per lane: LDS dest = wave-uniform base + lane*16
__device__ __forceinline__ void async_load16(const bf16* g, const bf16* lds_uniform) {
    __builtin_amdgcn_global_load_lds(
        (const __attribute__((address_space(1))) uint32_t*)(uintptr_t)g,
        (__attribute__((address_space(3))) uint32_t*)(uintptr_t)lds_uniform,
        16, 0, 0);
}

// pack two f32 -> one u32 of 2 bf16 (lo, hi); compiler emits v_cvt_pk_bf16_f32
__device__ __forceinline__ uint32_t pack2_bf16(float lo, float hi) {
    union { uint32_t u; __bf16 h[2]; } r;
    r.h[0] = (__bf16)lo;
    r.h[1] = (__bf16)hi;
    return r.u;
}

// gfx950: swap odd 16-lane rows of a with even 16-lane rows of b.
__device__ __forceinline__ void permswap16(uint32_t& a, uint32_t& b) {
    asm("v_permlane16_swap_b32 %0, %1" : "+v"(a), "+v"(b));
}

// ---------------------------------------------------------------- weight cast
__global__ __launch_bounds__(256) void cast4(const float* __restrict__ s0, bf16* __restrict__ d0,
                                             const float* __restrict__ s1, bf16* __restrict__ d1,
                                             const float* __restrict__ s2, bf16* __restrict__ d2,
                                             const float* __restrict__ s3, bf16* __restrict__ d3,
                                             int n4) {
    const float* s = blockIdx.y == 0 ? s0 : (blockIdx.y == 1 ? s1 : (blockIdx.y == 2 ? s2 : s3));
    bf16* d = blockIdx.y == 0 ? d0 : (blockIdx.y == 1 ? d1 : (blockIdx.y == 2 ? d2 : d3));
    int i = blockIdx.x * 256 + threadIdx.x;
    if (i < n4) {
        f32x4 v = ((const f32x4*)s)[i];
        bf16x4 o;
        o.x = (bf16)v.x; o.y = (bf16)v.y; o.z = (bf16)v.z; o.w = (bf16)v.w;
        ((bf16x4*)d)[i] = o;
    }
}

// ---------------------------------------------------------------- NT GEMM body (dbuf)
// C = (A * W^T + bias) * scale, M=8192 N=K=1024 hardcoded shape. 128x128 tile,
// BK=32, double-buffered LDS, next-tile loads issued BEFORE compute.
// LDS bank geometry (the round-4 lesson: 64B rows = 8-way read conflicts):
//  - AF32=1 A-path: manual f32->bf16 staging into As with ROW STRIDE 40 elems
//    (80B): row*20 mod 32 cycles 8 distinct bank bases -> writes conflict-free,
//    ds_read_b128 2-way (free). 80B keeps 16B alignment.
//  - Bs (and As when AF32=0) stay global_load_lds (linear LDS, 32-elem rows)
//    with PRE-SWIZZLED GLOBAL SOURCE: chunk c' = c ^ ((row>>1)&3); reads apply
//    the same XOR. 8-way -> 2-way.
// XCD swizzle pins A row-slices. VMODE=1: coalesced transposed per-head V write
// with key 8-block permutation (1<->2 within each 32) baked in so attn's
// permlane16_swap P-fragment matches V columns.
template <typename OutT, int VMODE, int AF32>
__device__ __forceinline__ void gemm_body(const void* __restrict__ Av,
                                          const bf16* __restrict__ W,
                                          const float* __restrict__ bias,
                                          OutT* __restrict__ C,
                                          int lin, float scale,
                                          bf16* As, bf16* Bs, bf16* Tt) {
    const int K = D_, N = D_;
    constexpr int AST = AF32 ? 40 : 32;   // As row stride (elems)
    constexpr int ABUFE = 128 * AST;      // As elems per dbuf
    const bf16* Ab = (const bf16*)Av;
    const float* Af = (const float*)Av;
    const int tid = threadIdx.x;
    const int wid = tid >> 6, lane = tid & 63;
    const int quad = lane >> 4, l15 = lane & 15;
    const int wm = (wid >> 1) * 64, wn = (wid & 1) * 64;
    const int bx = N >> 7;  // 8
    const int ty = (lin & 7) + 8 * (lin / (8 * bx));  // A-slice index (XCD-pinned)
    const int tx = (lin >> 3) % bx;                   // W-tile index (swept per XCD)
    const long rowA0 = (long)ty * 128;
    const long rowB0 = (long)tx * 128;
    const int srow = lane >> 2;          // async path: 16 rows, 4 chunks of 16B
    const int schunk = lane & 3;         // 16B chunk index
    const int srow4 = lane >> 3;         // f32 path: 8 rows, 8 chunks of 16B
    const int schunk4 = (lane & 7) * 4;  // f32 elems
    const int sbase = (wid * 32) * 32;   // per-wave segment in 32-elem-row bufs

    f32x4 acc[4][4];
#pragma unroll
    for (int i = 0; i < 4; i++)
#pragma unroll
        for (int j = 0; j < 4; j++) acc[i][j] = (f32x4){0.f, 0.f, 0.f, 0.f};

    // prologue: stage k-tile 0 into buffer 0
    if constexpr (AF32) {
        f32x4 a0[4];
#pragma unroll
        for (int s = 0; s < 4; s++) {
            int r = wid * 32 + s * 8 + srow4;
            a0[s] = *(const f32x4*)&Af[(rowA0 + r) * K + schunk4];
        }
#pragma unroll
        for (int s = 0; s < 2; s++) {
            int r = wid * 32 + s * 16 + srow;
            int sc = (schunk ^ ((r >> 1) & 3)) * 8;
            async_load16(&W[(rowB0 + r) * K + sc], &Bs[sbase + s * 16 * 32]);
        }
#pragma unroll
        for (int s = 0; s < 4; s++) {
            int r = wid * 32 + s * 8 + srow4;
            u32x2 w2 = {pack2_bf16(a0[s].x, a0[s].y), pack2_bf16(a0[s].z, a0[s].w)};
            *(u32x2*)&As[r * AST + schunk4] = w2;
        }
    } else {
#pragma unroll
        for (int s = 0; s < 2; s++) {
            int r = wid * 32 + s * 16 + srow;
            int sc = (schunk ^ ((r >> 1) & 3)) * 8;
            async_load16(&Ab[(rowA0 + r) * K + sc], &As[sbase + s * 16 * 32]);
            async_load16(&W[(rowB0 + r) * K + sc], &Bs[sbase + s * 16 * 32]);
        }
    }
    __syncthreads();

    const int NIT = K >> 5;  // 32
    for (int it = 0; it < NIT; it++) {
        const int cur = it & 1;
        const int coA = cur * ABUFE;
        const int coB = cur * (128 * 32);
        const int noA = (cur ^ 1) * ABUFE;
        const int noB = (cur ^ 1) * (128 * 32);
        f32x4 a_ld[4];
        if (it + 1 < NIT) {
            const int k1 = (it + 1) << 5;
            if constexpr (AF32) {
#pragma unroll
                for (int s = 0; s < 4; s++) {
                    int r = wid * 32 + s * 8 + srow4;
                    a_ld[s] = *(const f32x4*)&Af[(rowA0 + r) * K + k1 + schunk4];
                }
#pragma unroll
                for (int s = 0; s < 2; s++) {
                    int r = wid * 32 + s * 16 + srow;
                    int sc = (schunk ^ ((r >> 1) & 3)) * 8;
                    async_load16(&W[(rowB0 + r) * K + k1 + sc],
                                 &Bs[noB + sbase + s * 16 * 32]);
                }
            } else {
#pragma unroll
                for (int s = 0; s < 2; s++) {
                    int r = wid * 32 + s * 16 + srow;
                    int sc = (schunk ^ ((r >> 1) & 3)) * 8;
                    async_load16(&Ab[(rowA0 + r) * K + k1 + sc],
                                 &As[noA + sbase + s * 16 * 32]);
                    async_load16(&W[(rowB0 + r) * K + k1 + sc],
                                 &Bs[noB + sbase + s * 16 * 32]);
                }
            }
        }
        bf16x8 af[4], bfr[4];
#pragma unroll
        for (int i = 0; i < 4; i++) {
            int ra = wm + i * 16 + l15;
            if constexpr (AF32)
                af[i] = *(const bf16x8*)&As[coA + ra * AST + quad * 8];
            else
                af[i] = *(const bf16x8*)&As[coA + ra * 32 + ((quad ^ ((ra >> 1) & 3)) * 8)];
        }
#pragma unroll
        for (int j = 0; j < 4; j++) {
            int rb = wn + j * 16 + l15;
            bfr[j] = *(const bf16x8*)&Bs[coB + rb * 32 + ((quad ^ ((rb >> 1) & 3)) * 8)];
        }
#pragma unroll
        for (int i = 0; i < 4; i++)
#pragma unroll
            for (int j = 0; j < 4; j++)
                acc[i][j] = __builtin_amdgcn_mfma_f32_16x16x32_bf16(af[i], bfr[j],
                                                                    acc[i][j], 0, 0, 0);
        if constexpr (AF32) {
            if (it + 1 < NIT) {
#pragma unroll
                for (int s = 0; s < 4; s++) {
                    int r = wid * 32 + s * 8 + srow4;
                    u32x2 w2 = {pack2_bf16(a_ld[s].x, a_ld[s].y),
                                pack2_bf16(a_ld[s].z, a_ld[s].w)};
                    *(u32x2*)&As[noA + r * AST + schunk4] = w2;
                }
            }
        }
        __syncthreads();  // next-tile loads/writes drain here
    }

    if constexpr (VMODE == 0) {
#pragma unroll
        for (int i = 0; i < 4; i++) {
            long m = rowA0 + wm + i * 16 + quad * 4;
#pragma unroll
            for (int j = 0; j < 4; j++) {
                long n = rowB0 + wn + j * 16 + l15;
                float bb = bias[n];
#pragma unroll
                for (int r = 0; r < 4; r++) {
                    float v = (acc[i][j][r] + bb) * scale;
                    C[(m + r) * N + n] = (OutT)v;
                }
            }
        }
    } else {
        // Transpose C-tile through LDS -> coalesced VT[(b*H+h)*64+d][t] stores.
        // Tt overlays As/Bs: safe, all LDS reads of them finished at the loop's
        // final barrier.
#pragma unroll
        for (int i = 0; i < 4; i++) {
            int ml = wm + i * 16 + quad * 4;
#pragma unroll
            for (int j = 0; j < 4; j++) {
                int nl = wn + j * 16 + l15;
                float bb = bias[rowB0 + nl];
                bf16x4 ov = {(bf16)(acc[i][j][0] + bb), (bf16)(acc[i][j][1] + bb),
                             (bf16)(acc[i][j][2] + bb), (bf16)(acc[i][j][3] + bb)};
                *(bf16x4*)&Tt[nl * 136 + ml] = ov;
            }
        }
        __syncthreads();
        const long bidx = rowA0 >> 11;        // batch
        const int t0 = (int)(rowA0 & 2047);   // t within batch
#pragma unroll
        for (int p = 0; p < 8; p++) {
            int nl = p * 16 + (tid >> 4);
            int c = tid & 15;
            bf16x8 val = *(const bf16x8*)&Tt[nl * 136 + c * 8];
            int n = (int)rowB0 + nl;
            long vrow = (bidx * H_ + (n >> 6)) * (long)HD_ + (n & 63);
            // key 8-block permutation: within each 32-key group swap blocks 1<->2
            int cp = (c & ~3) | ((c & 1) << 1) | ((c & 2) >> 1);
            *(bf16x8*)&((bf16*)C)[vrow * T_ + t0 + cp * 8] = val;
        }
    }
}

// fused Q/K/V projection from RAW f32 inputs (cast fused into A-staging):
// 3 x 512 blocks in one launch. As padded (20480B) + Bs (16384B) = 36864B;
// Tt (34816B) overlays.
__global__ __launch_bounds__(256) void gemm_qkv(const float* __restrict__ q,
                                                const bf16* __restrict__ WqB,
                                                const float* __restrict__ bq,
                                                bf16* __restrict__ Qp,
                                                const float* __restrict__ k,
                                                const bf16* __restrict__ WkB,
                                                const float* __restrict__ bk,
                                                bf16* __restrict__ Kp,
                                                const float* __restrict__ v,
                                                const bf16* __restrict__ WvB,
                                                const float* __restrict__ bv,
                                                bf16* __restrict__ VtG) {
    __shared__ __align__(16) char sm[36864];
    bf16* As = (bf16*)sm;
    bf16* Bs = (bf16*)(sm + 20480);
    bf16* Tt = (bf16*)sm;
    const int p = blockIdx.x >> 9;
    const int lin = blockIdx.x & 511;
    if (p == 0)
        gemm_body<bf16, 0, 1>(q, WqB, bq, Qp, lin, QSCALE, As, Bs, Tt);
    else if (p == 1)
        gemm_body<bf16, 0, 1>(k, WkB, bk, Kp, lin, 1.f, As, Bs, Tt);
    else
        gemm_body<bf16, 1, 1>(v, WvB, bv, VtG, lin, 1.f, As, Bs, Tt);
}

__global__ __launch_bounds__(256) void gemm_out(const bf16* __restrict__ Op,
                                                const bf16* __restrict__ WoB,
                                                const float* __restrict__ bo,
                                                float* __restrict__ out) {
    __shared__ __align__(16) char sm[32768];
    bf16* As = (bf16*)sm;
    bf16* Bs = (bf16*)(sm + 16384);
    gemm_body<float, 0, 0>(Op, WoB, bo, out, blockIdx.x, 1.f, As, Bs, nullptr);
}

// ---------------------------------------------------------------- flash attention (S^T form)
// (unchanged from round 4 -- isolates this round's GEMM delta)
// 512 threads = 8 waves x 16 q = 128 q/block; grid = B*H*(T/128) = 1024 blocks
// = 4 blocks/CU = 32 waves/CU. 8 waves share the 64x64 K/V staging tiles.
// S^T = K*Q^T so q = MFMA col (l15). P never touches LDS: exp2(S) packed to
// bf16 pairs in-register + one v_permlane16_swap_b32 per pair -> PV B-fragment
// with key order {0-7,16-23,8-15,24-31} per quad; matching key 8-block
// permutation is baked into VT by the V-projection GEMM. lsum rides the MFMA
// pipe via an all-ones A-fragment. PHASE STAGGER: odd waves process the key
// halves in reverse order.
__global__ __launch_bounds__(512, 8) void attn_kernel(const bf16* __restrict__ Qp,
                                                      const bf16* __restrict__ Kp,
                                                      const bf16* __restrict__ VT,
                                                      bf16* __restrict__ Op) {
    __shared__ bf16 smem[4][64 * 64];  // [0..1]=K dbuf, [2..3]=V dbuf; epilogue scratch
    const int tid = threadIdx.x;
    const int wid = tid >> 6, lane = tid & 63;   // wid 0..7
    const int quad = lane >> 4, l15 = lane & 15;
    const int q7 = l15 & 7;
    const int lin = blockIdx.x;
    const int bh = (lin & 7) + 8 * (lin >> 7);  // XCD-pinned head (1024 blocks)
    const int qt = (lin >> 3) & 15;             // 16 q-tiles of 128, swept within XCD
    const int b = bh >> 4, h = bh & 15;
    const long tok0 = (long)b * T_ + (long)qt * 128 + wid * 16;
    const int hcol = h * HD_;
    const long vrow0 = ((long)bh) * HD_;
    const int g_sw = ((lane & 7) ^ (lane >> 3)) * 8;
    const int srow = lane >> 3;
    const int sbase = (wid * 8) * 64;  // each wave stages 8 rows of the 64-row tiles

    // preload kt=0 staging (1 K-row-block + 1 V-row-block per wave)
    {
        const long krow0 = (long)b * T_;
        const int r = wid * 8 + srow;
        async_load16(&Kp[(krow0 + r) * D_ + hcol + g_sw], &smem[0][sbase]);
        async_load16(&VT[(vrow0 + r) * T_ + g_sw], &smem[2][sbase]);
    }

    // Q B-frags (n = q = l15, k = d): persistent; Qp already scaled by 0.125*log2e
    bf16x8 bq0 = *(const bf16x8*)&Qp[(tok0 + l15) * D_ + hcol + quad * 8];
    bf16x8 bq1 = *(const bf16x8*)&Qp[(tok0 + l15) * D_ + hcol + 32 + quad * 8];

    // all-ones A-frag for the lsum MFMA (bf16 1.0 pairs)
    const u32x4 onesu = {0x3F803F80u, 0x3F803F80u, 0x3F803F80u, 0x3F803F80u};
    const bf16x8 ones = __builtin_bit_cast(bf16x8, onesu);

    f32x4 o[4];  // o[mt] = O^T[d=mt*16+quad*4+r][q=l15]
#pragma unroll
    for (int mt = 0; mt < 4; mt++) o[mt] = (f32x4){0.f, 0.f, 0.f, 0.f};
    f32x4 ls = (f32x4){0.f, 0.f, 0.f, 0.f};  // all 4 elements identical = sum_k P[k][q]

    __syncthreads();  // drain preload

    const int h0 = wid & 1;  // phase stagger: odd waves start with keys 32..63

    for (int kt = 0; kt < NKT; kt++) {
        const int cur = kt & 1;
        // issue NEXT tile's staging now; compute below hides its latency
        if (kt + 1 < NKT) {
            const long krow1 = (long)b * T_ + (long)(kt + 1) * 64;
            const int nb = cur ^ 1;
            const int r = wid * 8 + srow;
            async_load16(&Kp[(krow1 + r) * D_ + hcol + g_sw], &smem[nb][sbase]);
            async_load16(&VT[(vrow0 + r) * T_ + (long)(kt + 1) * 64 + g_sw],
                         &smem[2 + nb][sbase]);
        }
        const bf16* Ksc = smem[cur];
        const bf16* Vsc = smem[2 + cur];

        // one 32-key half: S^T -> exp2 -> pack -> permlane-swap -> lsum + PV
        auto half_step = [&](int hh) {
            uint32_t pA[2], pB[2];
#pragma unroll
            for (int mt = 0; mt < 2; mt++) {
                const bf16* kr = &Ksc[(hh * 32 + mt * 16 + l15) * 64];
                bf16x8 ak0 = *(const bf16x8*)&kr[(quad ^ q7) * 8];
                bf16x8 ak1 = *(const bf16x8*)&kr[((4 + quad) ^ q7) * 8];
                f32x4 s = {0.f, 0.f, 0.f, 0.f};
                s = __builtin_amdgcn_mfma_f32_16x16x32_bf16(ak0, bq0, s, 0, 0, 0);
                s = __builtin_amdgcn_mfma_f32_16x16x32_bf16(ak1, bq1, s, 0, 0, 0);
                float p0 = fast_exp2(s[0]), p1 = fast_exp2(s[1]);
                float p2 = fast_exp2(s[2]), p3 = fast_exp2(s[3]);
                pA[mt] = pack2_bf16(p0, p1);
                pB[mt] = pack2_bf16(p2, p3);
            }
            permswap16(pA[0], pA[1]);
            permswap16(pB[0], pB[1]);
            u32x4 f = {pA[0], pB[0], pA[1], pB[1]};
            bf16x8 pb = __builtin_bit_cast(bf16x8, f);
            ls = __builtin_amdgcn_mfma_f32_16x16x32_bf16(ones, pb, ls, 0, 0, 0);
            const int vch = ((hh * 4 + quad) ^ q7) * 8;
#pragma unroll
            for (int mt = 0; mt < 4; mt++) {
                bf16x8 av = *(const bf16x8*)&Vsc[(mt * 16 + l15) * 64 + vch];
                o[mt] = __builtin_amdgcn_mfma_f32_16x16x32_bf16(av, pb, o[mt], 0, 0, 0);
            }
        };
        half_step(h0);
        half_step(h0 ^ 1);
        __syncthreads();  // next-tile loads (issued pre-compute) drain here ~free
    }

    // ls already holds the full key-sum for q=l15 (MFMA reduced over k); no shfl needed
    const float linv = 1.f / ls[0];

    // epilogue: O^T -> [q][d] via wave-private swizzled LDS (reuse K/V buffers;
    // all waves' K/V reads finished at the loop's final barrier)
    bf16* ew = (bf16*)smem + wid * (16 * 64);
#pragma unroll
    for (int mt = 0; mt < 4; mt++) {
        bf16x4 ov = {(bf16)(o[mt][0] * linv), (bf16)(o[mt][1] * linv),
                     (bf16)(o[mt][2] * linv), (bf16)(o[mt][3] * linv)};
        *(bf16x4*)&ew[l15 * 64 + (((mt * 2 + (quad >> 1)) ^ q7) * 8) + (quad & 1) * 4] = ov;
    }
#pragma unroll
    for (int p2 = 0; p2 < 2; p2++) {
        int q = p2 * 8 + (lane >> 3);
        int dc = lane & 7;
        bf16x8 ov = *(const bf16x8*)&ew[q * 64 + ((dc ^ (q & 7)) * 8)];
        *(bf16x8*)&Op[(tok0 + q) * D_ + hcol + dc * 8] = ov;
    }
}

// ---------------------------------------------------------------- launch
extern "C" void kernel_launch(void* const* d_in, const int* in_sizes, int n_in,
                              void* d_out, int out_size, void* d_ws, size_t ws_size,
                              hipStream_t stream) {
    const float* q  = (const float*)d_in[0];
    const float* k  = (const float*)d_in[1];
    const float* v  = (const float*)d_in[2];
    const float* Wq = (const float*)d_in[3];
    const float* bq = (const float*)d_in[4];
    const float* Wk = (const float*)d_in[5];
    const float* bk = (const float*)d_in[6];
    const float* Wv = (const float*)d_in[7];
    const float* bv = (const float*)d_in[8];
    const float* Wo = (const float*)d_in[9];
    const float* bo = (const float*)d_in[10];
    float* out = (float*)d_out;

    const size_t MD = (size_t)B_ * T_ * D_;  // 8388608
    const size_t DD = (size_t)D_ * D_;
    char* ws = (char*)d_ws;
    bf16* WqB = (bf16*)ws; ws += DD * 2;
    bf16* WkB = (bf16*)ws; ws += DD * 2;
    bf16* WvB = (bf16*)ws; ws += DD * 2;
    bf16* WoB = (bf16*)ws; ws += DD * 2;
    bf16* Qp  = (bf16*)ws; ws += MD * 2;
    bf16* Kp  = (bf16*)ws; ws += MD * 2;
    bf16* VtG = (bf16*)ws; ws += MD * 2;
    bf16* Op  = (bf16*)ws; ws += MD * 2;

    cast4<<<dim3(DD / 4 / 256, 4), 256, 0, stream>>>(Wq, WqB, Wk, WkB, Wv, WvB, Wo, WoB, DD / 4);

    gemm_qkv<<<3 * 512, 256, 0, stream>>>(q, WqB, bq, Qp, k, WkB, bk, Kp, v, WvB, bv, VtG);

    attn_kernel<<<B_ * H_ * (T_ / 128), 512, 0, stream>>>(Qp, Kp, VtG, Op);

    gemm_out<<<512, 256, 0, stream>>>(Op, WoB, bo, out);
}

// Round 6
// 336.619 us; speedup vs baseline: 1.0715x; 1.0715x over previous
//
#include <hip/hip_runtime.h>
#include <hip/hip_bf16.h>
#include <stdint.h>

#define B_ 4
#define T_ 2048
#define D_ 1024
#define H_ 16
#define HD_ 64
#define NKT (T_ / 64)

typedef __bf16 bf16;
typedef __bf16 bf16x8 __attribute__((ext_vector_type(8)));
typedef __bf16 bf16x4 __attribute__((ext_vector_type(4)));
typedef float f32x4 __attribute__((ext_vector_type(4)));
typedef uint32_t u32x4 __attribute__((ext_vector_type(4)));

// 0.125 (1/sqrt(64)) * log2(e): folded into Q projection so attn uses native exp2
#define QSCALE 0.18033688011112042f

__device__ __forceinline__ float fast_exp2(float x) {
#if __has_builtin(__builtin_amdgcn_exp2f)
    return __builtin_amdgcn_exp2f(x);
#else
    return exp2f(x);
#endif
}

// async global->LDS, 16B per lane: LDS dest = wave-uniform base + lane*16
__device__ __forceinline__ void async_load16(const bf16* g, const bf16* lds_uniform) {
    __builtin_amdgcn_global_load_lds(
        (const __attribute__((address_space(1))) uint32_t*)(uintptr_t)g,
        (__attribute__((address_space(3))) uint32_t*)(uintptr_t)lds_uniform,
        16, 0, 0);
}

// pack two f32 -> one u32 of 2 bf16 (lo, hi); compiler emits v_cvt_pk_bf16_f32
__device__ __forceinline__ uint32_t pack2_bf16(float lo, float hi) {
    union { uint32_t u; __bf16 h[2]; } r;
    r.h[0] = (__bf16)lo;
    r.h[1] = (__bf16)hi;
    return r.u;
}

// gfx950: swap odd 16-lane rows of a with even 16-lane rows of b.
__device__ __forceinline__ void permswap16(uint32_t& a, uint32_t& b) {
    asm("v_permlane16_swap_b32 %0, %1" : "+v"(a), "+v"(b));
}

// ---------------------------------------------------------------- all casts, one launch
// y=0..2: q/k/v (2M f32x4 each); y=3: the four DD weights back-to-back.
__global__ __launch_bounds__(256) void cast_all(const float* __restrict__ q, bf16* __restrict__ dq,
                                                const float* __restrict__ k, bf16* __restrict__ dk,
                                                const float* __restrict__ v, bf16* __restrict__ dv,
                                                const float* __restrict__ w0, bf16* __restrict__ e0,
                                                const float* __restrict__ w1, bf16* __restrict__ e1,
                                                const float* __restrict__ w2, bf16* __restrict__ e2,
                                                const float* __restrict__ w3, bf16* __restrict__ e3) {
    long i = blockIdx.x * 256 + threadIdx.x;  // f32x4 index
    const float* s;
    bf16* d;
    if (blockIdx.y < 3) {
        s = blockIdx.y == 0 ? q : (blockIdx.y == 1 ? k : v);
        d = blockIdx.y == 0 ? dq : (blockIdx.y == 1 ? dk : dv);
    } else {
        const long per = (long)(D_ * D_) / 4;  // 262144 f32x4 per weight
        long wsel = i / per;
        if (wsel >= 4) return;
        i -= wsel * per;
        s = wsel == 0 ? w0 : (wsel == 1 ? w1 : (wsel == 2 ? w2 : w3));
        d = wsel == 0 ? e0 : (wsel == 1 ? e1 : (wsel == 2 ? e2 : e3));
    }
    f32x4 val = ((const f32x4*)s)[i];
    bf16x4 o;
    o.x = (bf16)val.x; o.y = (bf16)val.y; o.z = (bf16)val.z; o.w = (bf16)val.w;
    ((bf16x4*)d)[i] = o;
}

// ---------------------------------------------------------------- NT GEMM body (dbuf)
// C = (A * W^T + bias) * scale, M=8192 N=K=1024 hardcoded shape. 128x128 tile,
// BK=32, double-buffered LDS, next-tile global_load_lds issued BEFORE compute
// (single barrier/iter finds loads complete). XCD swizzle pins A row-slices.
// VMODE=1: coalesced transposed per-head V write via a TWO-PASS per-64-row LDS
// transpose tile (17408B, overlays As/Bs) so kernel LDS stays 32768 -> 5
// blocks/CU. Key 8-block permutation (1<->2 within each 32) baked into the V
// store so attn's permlane16_swap P-fragment matches V columns.
template <typename OutT, int VMODE>
__device__ __forceinline__ void gemm_body(const bf16* __restrict__ A,
                                          const bf16* __restrict__ W,
                                          const float* __restrict__ bias,
                                          OutT* __restrict__ C,
                                          int lin, float scale,
                                          bf16* As, bf16* Bs, bf16* Tt) {
    const int K = D_, N = D_;
    const int tid = threadIdx.x;
    const int wid = tid >> 6, lane = tid & 63;
    const int quad = lane >> 4, l15 = lane & 15;
    const int wm = (wid >> 1) * 64, wn = (wid & 1) * 64;
    const int bx = N >> 7;  // 8
    const int ty = (lin & 7) + 8 * (lin / (8 * bx));  // A-slice index (XCD-pinned)
    const int tx = (lin >> 3) % bx;                   // W-tile index (swept per XCD)
    const long rowA0 = (long)ty * 128;
    const long rowB0 = (long)tx * 128;
    const int srow = lane >> 2;
    const int schunk = (lane & 3) * 8;
    const int sbase = (wid * 32) * 32;

    f32x4 acc[4][4];
#pragma unroll
    for (int i = 0; i < 4; i++)
#pragma unroll
        for (int j = 0; j < 4; j++) acc[i][j] = (f32x4){0.f, 0.f, 0.f, 0.f};

    // prologue: stage k-tile 0 into buffer 0
#pragma unroll
    for (int s = 0; s < 2; s++) {
        int r = wid * 32 + s * 16 + srow;
        async_load16(&A[(rowA0 + r) * K + schunk], &As[sbase + s * 16 * 32]);
        async_load16(&W[(rowB0 + r) * K + schunk], &Bs[sbase + s * 16 * 32]);
    }
    __syncthreads();

    const int NIT = K >> 5;  // 32
    for (int it = 0; it < NIT; it++) {
        const int cur = it & 1;
        const int co = cur * (128 * 32);
        if (it + 1 < NIT) {
            const int k1 = (it + 1) << 5;
            const int no = (cur ^ 1) * (128 * 32);
#pragma unroll
            for (int s = 0; s < 2; s++) {
                int r = wid * 32 + s * 16 + srow;
                async_load16(&A[(rowA0 + r) * K + k1 + schunk], &As[no + sbase + s * 16 * 32]);
                async_load16(&W[(rowB0 + r) * K + k1 + schunk], &Bs[no + sbase + s * 16 * 32]);
            }
        }
        bf16x8 af[4], bfr[4];
#pragma unroll
        for (int i = 0; i < 4; i++)
            af[i] = *(const bf16x8*)&As[co + (wm + i * 16 + l15) * 32 + quad * 8];
#pragma unroll
        for (int j = 0; j < 4; j++)
            bfr[j] = *(const bf16x8*)&Bs[co + (wn + j * 16 + l15) * 32 + quad * 8];
#pragma unroll
        for (int i = 0; i < 4; i++)
#pragma unroll
            for (int j = 0; j < 4; j++)
                acc[i][j] = __builtin_amdgcn_mfma_f32_16x16x32_bf16(af[i], bfr[j],
                                                                    acc[i][j], 0, 0, 0);
        __syncthreads();  // next-tile loads (issued pre-compute) drain ~free
    }

    if constexpr (VMODE == 0) {
#pragma unroll
        for (int i = 0; i < 4; i++) {
            long m = rowA0 + wm + i * 16 + quad * 4;
#pragma unroll
            for (int j = 0; j < 4; j++) {
                long n = rowB0 + wn + j * 16 + l15;
                float bb = bias[n];
#pragma unroll
                for (int r = 0; r < 4; r++) {
                    float v = (acc[i][j][r] + bb) * scale;
                    C[(m + r) * N + n] = (OutT)v;
                }
            }
        }
    } else {
        // Two-pass transpose -> coalesced VT[(b*H+h)*64+d][t] stores.
        // Pass p2 handles n&63 in [p2*32, p2*32+32) (j = 2*p2, 2*p2+1):
        // 64 n-rows x 128 m in a 64x136 tile (17408B, overlays As/Bs).
        // Write rr = (nl&31) + (nl>>6)*32; read rr == idx identically.
        const long bidx = rowA0 >> 11;        // batch
        const int t0 = (int)(rowA0 & 2047);   // t within batch
#pragma unroll
        for (int p2 = 0; p2 < 2; p2++) {
            if (p2) __syncthreads();  // protect tile reuse from pass-0 reads
#pragma unroll
            for (int j2 = 0; j2 < 2; j2++) {
                int j = p2 * 2 + j2;
                int nl = wn + j * 16 + l15;
                int rr = (nl & 31) + ((nl >> 6) << 5);
                float bb = bias[rowB0 + nl];
#pragma unroll
                for (int i = 0; i < 4; i++) {
                    int ml = wm + i * 16 + quad * 4;
                    bf16x4 ov = {(bf16)(acc[i][j][0] + bb), (bf16)(acc[i][j][1] + bb),
                                 (bf16)(acc[i][j][2] + bb), (bf16)(acc[i][j][3] + bb)};
                    *(bf16x4*)&Tt[rr * 136 + ml] = ov;
                }
            }
            __syncthreads();
#pragma unroll
            for (int p = 0; p < 4; p++) {
                int idx = p * 16 + (tid >> 4);
                int c = tid & 15;
                bf16x8 val = *(const bf16x8*)&Tt[idx * 136 + c * 8];
                int n = (int)rowB0 + (idx & 31) + p2 * 32 + ((idx >> 5) << 6);
                long vrow = (bidx * H_ + (n >> 6)) * (long)HD_ + (n & 63);
                // key 8-block permutation: within each 32-key group swap blocks 1<->2
                int cp = (c & ~3) | ((c & 1) << 1) | ((c & 2) >> 1);
                *(bf16x8*)&((bf16*)C)[vrow * T_ + t0 + cp * 8] = val;
            }
        }
    }
}

// fused Q/K/V projection: 3 x 512 blocks in one launch. LDS exactly 32768
// (two-pass V epilogue overlays) -> 5 blocks/CU.
__global__ __launch_bounds__(256) void gemm_qkv(const bf16* __restrict__ Xq,
                                                const bf16* __restrict__ WqB,
                                                const float* __restrict__ bq,
                                                bf16* __restrict__ Qp,
                                                const bf16* __restrict__ Xk,
                                                const bf16* __restrict__ WkB,
                                                const float* __restrict__ bk,
                                                bf16* __restrict__ Kp,
                                                const bf16* __restrict__ Xv,
                                                const bf16* __restrict__ WvB,
                                                const float* __restrict__ bv,
                                                bf16* __restrict__ VtG) {
    __shared__ __align__(16) char sm[32768];
    bf16* As = (bf16*)sm;
    bf16* Bs = (bf16*)(sm + 16384);
    bf16* Tt = (bf16*)sm;
    const int p = blockIdx.x >> 9;
    const int lin = blockIdx.x & 511;
    if (p == 0)
        gemm_body<bf16, 0>(Xq, WqB, bq, Qp, lin, QSCALE, As, Bs, Tt);
    else if (p == 1)
        gemm_body<bf16, 0>(Xk, WkB, bk, Kp, lin, 1.f, As, Bs, Tt);
    else
        gemm_body<bf16, 1>(Xv, WvB, bv, VtG, lin, 1.f, As, Bs, Tt);
}

__global__ __launch_bounds__(256) void gemm_out(const bf16* __restrict__ Op,
                                                const bf16* __restrict__ WoB,
                                                const float* __restrict__ bo,
                                                float* __restrict__ out) {
    __shared__ __align__(16) char sm[32768];
    bf16* As = (bf16*)sm;
    bf16* Bs = (bf16*)(sm + 16384);
    gemm_body<float, 0>(Op, WoB, bo, out, blockIdx.x, 1.f, As, Bs, nullptr);
}

// ---------------------------------------------------------------- flash attention (S^T form)
// (unchanged from rounds 4/5 -- its dur finally becomes visible again this round)
// 512 threads = 8 waves x 16 q = 128 q/block; grid = B*H*(T/128) = 1024 blocks
// = 4 blocks/CU = 32 waves/CU. 8 waves share the 64x64 K/V staging tiles.
// S^T = K*Q^T so q = MFMA col (l15). P never touches LDS: exp2(S) packed to
// bf16 pairs in-register + one v_permlane16_swap_b32 per pair -> PV B-fragment
// with key order {0-7,16-23,8-15,24-31} per quad; matching key 8-block
// permutation is baked into VT by the V-projection GEMM. lsum rides the MFMA
// pipe via an all-ones A-fragment. PHASE STAGGER: odd waves process the key
// halves in reverse order.
__global__ __launch_bounds__(512, 8) void attn_kernel(const bf16* __restrict__ Qp,
                                                      const bf16* __restrict__ Kp,
                                                      const bf16* __restrict__ VT,
                                                      bf16* __restrict__ Op) {
    __shared__ bf16 smem[4][64 * 64];  // [0..1]=K dbuf, [2..3]=V dbuf; epilogue scratch
    const int tid = threadIdx.x;
    const int wid = tid >> 6, lane = tid & 63;   // wid 0..7
    const int quad = lane >> 4, l15 = lane & 15;
    const int q7 = l15 & 7;
    const int lin = blockIdx.x;
    const int bh = (lin & 7) + 8 * (lin >> 7);  // XCD-pinned head (1024 blocks)
    const int qt = (lin >> 3) & 15;             // 16 q-tiles of 128, swept within XCD
    const int b = bh >> 4, h = bh & 15;
    const long tok0 = (long)b * T_ + (long)qt * 128 + wid * 16;
    const int hcol = h * HD_;
    const long vrow0 = ((long)bh) * HD_;
    const int g_sw = ((lane & 7) ^ (lane >> 3)) * 8;
    const int srow = lane >> 3;
    const int sbase = (wid * 8) * 64;  // each wave stages 8 rows of the 64-row tiles

    // preload kt=0 staging (1 K-row-block + 1 V-row-block per wave)
    {
        const long krow0 = (long)b * T_;
        const int r = wid * 8 + srow;
        async_load16(&Kp[(krow0 + r) * D_ + hcol + g_sw], &smem[0][sbase]);
        async_load16(&VT[(vrow0 + r) * T_ + g_sw], &smem[2][sbase]);
    }

    // Q B-frags (n = q = l15, k = d): persistent; Qp already scaled by 0.125*log2e
    bf16x8 bq0 = *(const bf16x8*)&Qp[(tok0 + l15) * D_ + hcol + quad * 8];
    bf16x8 bq1 = *(const bf16x8*)&Qp[(tok0 + l15) * D_ + hcol + 32 + quad * 8];

    // all-ones A-frag for the lsum MFMA (bf16 1.0 pairs)
    const u32x4 onesu = {0x3F803F80u, 0x3F803F80u, 0x3F803F80u, 0x3F803F80u};
    const bf16x8 ones = __builtin_bit_cast(bf16x8, onesu);

    f32x4 o[4];  // o[mt] = O^T[d=mt*16+quad*4+r][q=l15]
#pragma unroll
    for (int mt = 0; mt < 4; mt++) o[mt] = (f32x4){0.f, 0.f, 0.f, 0.f};
    f32x4 ls = (f32x4){0.f, 0.f, 0.f, 0.f};  // all 4 elements identical = sum_k P[k][q]

    __syncthreads();  // drain preload

    const int h0 = wid & 1;  // phase stagger: odd waves start with keys 32..63

    for (int kt = 0; kt < NKT; kt++) {
        const int cur = kt & 1;
        // issue NEXT tile's staging now; compute below hides its latency
        if (kt + 1 < NKT) {
            const long krow1 = (long)b * T_ + (long)(kt + 1) * 64;
            const int nb = cur ^ 1;
            const int r = wid * 8 + srow;
            async_load16(&Kp[(krow1 + r) * D_ + hcol + g_sw], &smem[nb][sbase]);
            async_load16(&VT[(vrow0 + r) * T_ + (long)(kt + 1) * 64 + g_sw],
                         &smem[2 + nb][sbase]);
        }
        const bf16* Ksc = smem[cur];
        const bf16* Vsc = smem[2 + cur];

        // one 32-key half: S^T -> exp2 -> pack -> permlane-swap -> lsum + PV
        auto half_step = [&](int hh) {
            uint32_t pA[2], pB[2];
#pragma unroll
            for (int mt = 0; mt < 2; mt++) {
                const bf16* kr = &Ksc[(hh * 32 + mt * 16 + l15) * 64];
                bf16x8 ak0 = *(const bf16x8*)&kr[(quad ^ q7) * 8];
                bf16x8 ak1 = *(const bf16x8*)&kr[((4 + quad) ^ q7) * 8];
                f32x4 s = {0.f, 0.f, 0.f, 0.f};
                s = __builtin_amdgcn_mfma_f32_16x16x32_bf16(ak0, bq0, s, 0, 0, 0);
                s = __builtin_amdgcn_mfma_f32_16x16x32_bf16(ak1, bq1, s, 0, 0, 0);
                float p0 = fast_exp2(s[0]), p1 = fast_exp2(s[1]);
                float p2 = fast_exp2(s[2]), p3 = fast_exp2(s[3]);
                pA[mt] = pack2_bf16(p0, p1);
                pB[mt] = pack2_bf16(p2, p3);
            }
            permswap16(pA[0], pA[1]);
            permswap16(pB[0], pB[1]);
            u32x4 f = {pA[0], pB[0], pA[1], pB[1]};
            bf16x8 pb = __builtin_bit_cast(bf16x8, f);
            ls = __builtin_amdgcn_mfma_f32_16x16x32_bf16(ones, pb, ls, 0, 0, 0);
            const int vch = ((hh * 4 + quad) ^ q7) * 8;
#pragma unroll
            for (int mt = 0; mt < 4; mt++) {
                bf16x8 av = *(const bf16x8*)&Vsc[(mt * 16 + l15) * 64 + vch];
                o[mt] = __builtin_amdgcn_mfma_f32_16x16x32_bf16(av, pb, o[mt], 0, 0, 0);
            }
        };
        half_step(h0);
        half_step(h0 ^ 1);
        __syncthreads();  // next-tile loads (issued pre-compute) drain here ~free
    }

    // ls already holds the full key-sum for q=l15 (MFMA reduced over k); no shfl needed
    const float linv = 1.f / ls[0];

    // epilogue: O^T -> [q][d] via wave-private swizzled LDS (reuse K/V buffers;
    // all waves' K/V reads finished at the loop's final barrier)
    bf16* ew = (bf16*)smem + wid * (16 * 64);
#pragma unroll
    for (int mt = 0; mt < 4; mt++) {
        bf16x4 ov = {(bf16)(o[mt][0] * linv), (bf16)(o[mt][1] * linv),
                     (bf16)(o[mt][2] * linv), (bf16)(o[mt][3] * linv)};
        *(bf16x4*)&ew[l15 * 64 + (((mt * 2 + (quad >> 1)) ^ q7) * 8) + (quad & 1) * 4] = ov;
    }
#pragma unroll
    for (int p2 = 0; p2 < 2; p2++) {
        int q = p2 * 8 + (lane >> 3);
        int dc = lane & 7;
        bf16x8 ov = *(const bf16x8*)&ew[q * 64 + ((dc ^ (q & 7)) * 8)];
        *(bf16x8*)&Op[(tok0 + q) * D_ + hcol + dc * 8] = ov;
    }
}

// ---------------------------------------------------------------- launch
extern "C" void kernel_launch(void* const* d_in, const int* in_sizes, int n_in,
                              void* d_out, int out_size, void* d_ws, size_t ws_size,
                              hipStream_t stream) {
    const float* q  = (const float*)d_in[0];
    const float* k  = (const float*)d_in[1];
    const float* v  = (const float*)d_in[2];
    const float* Wq = (const float*)d_in[3];
    const float* bq = (const float*)d_in[4];
    const float* Wk = (const float*)d_in[5];
    const float* bk = (const float*)d_in[6];
    const float* Wv = (const float*)d_in[7];
    const float* bv = (const float*)d_in[8];
    const float* Wo = (const float*)d_in[9];
    const float* bo = (const float*)d_in[10];
    float* out = (float*)d_out;

    const size_t MD = (size_t)B_ * T_ * D_;  // 8388608
    const size_t DD = (size_t)D_ * D_;
    char* ws = (char*)d_ws;
    bf16* Xq  = (bf16*)ws; ws += MD * 2;
    bf16* Xk  = (bf16*)ws; ws += MD * 2;
    bf16* Xv  = (bf16*)ws; ws += MD * 2;
    bf16* WqB = (bf16*)ws; ws += DD * 2;
    bf16* WkB = (bf16*)ws; ws += DD * 2;
    bf16* WvB = (bf16*)ws; ws += DD * 2;
    bf16* WoB = (bf16*)ws; ws += DD * 2;
    bf16* Qp  = (bf16*)ws; ws += MD * 2;
    bf16* Kp  = (bf16*)ws; ws += MD * 2;
    bf16* VtG = (bf16*)ws; ws += MD * 2;
    bf16* Op  = (bf16*)ws; ws += MD * 2;

    cast_all<<<dim3(MD / 4 / 256, 4), 256, 0, stream>>>(q, Xq, k, Xk, v, Xv,
                                                        Wq, WqB, Wk, WkB, Wv, WvB, Wo, WoB);

    gemm_qkv<<<3 * 512, 256, 0, stream>>>(Xq, WqB, bq, Qp, Xk, WkB, bk, Kp, Xv, WvB, bv, VtG);

    attn_kernel<<<B_ * H_ * (T_ / 128), 512, 0, stream>>>(Qp, Kp, VtG, Op);

    gemm_out<<<512, 256, 0, stream>>>(Op, WoB, bo, out);
}

// Round 8
// 331.467 us; speedup vs baseline: 1.0881x; 1.0155x over previous
//
#include <hip/hip_runtime.h>
#include <hip/hip_bf16.h>
#include <stdint.h>

#define B_ 4
#define T_ 2048
#define D_ 1024
#define H_ 16
#define HD_ 64
#define NKT (T_ / 64)

typedef __bf16 bf16;
typedef __bf16 bf16x8 __attribute__((ext_vector_type(8)));
typedef __bf16 bf16x4 __attribute__((ext_vector_type(4)));
typedef float f32x4 __attribute__((ext_vector_type(4)));
typedef uint32_t u32x4 __attribute__((ext_vector_type(4)));

// 0.125 (1/sqrt(64)) * log2(e): folded into Q projection so attn uses native exp2
#define QSCALE 0.18033688011112042f

__device__ __forceinline__ float fast_exp2(float x) {
#if __has_builtin(__builtin_amdgcn_exp2f)
    return __builtin_amdgcn_exp2f(x);
#else
    return exp2f(x);
#endif
}

// async global->LDS, 16B per lane: LDS dest = wave-uniform base + lane*16
__device__ __forceinline__ void async_load16(const bf16* g, const bf16* lds_uniform) {
    __builtin_amdgcn_global_load_lds(
        (const __attribute__((address_space(1))) uint32_t*)(uintptr_t)g,
        (__attribute__((address_space(3))) uint32_t*)(uintptr_t)lds_uniform,
        16, 0, 0);
}

// pack two f32 -> one u32 of 2 bf16 (lo, hi); compiler emits v_cvt_pk_bf16_f32
__device__ __forceinline__ uint32_t pack2_bf16(float lo, float hi) {
    union { uint32_t u; __bf16 h[2]; } r;
    r.h[0] = (__bf16)lo;
    r.h[1] = (__bf16)hi;
    return r.u;
}

// gfx950: swap odd 16-lane rows of a with even 16-lane rows of b.
__device__ __forceinline__ void permswap16(uint32_t& a, uint32_t& b) {
    asm("v_permlane16_swap_b32 %0, %1" : "+v"(a), "+v"(b));
}

// ---------------------------------------------------------------- all casts, one launch
// y=0..2: q/k/v (2M f32x4 each); y=3: the four DD weights back-to-back.
__global__ __launch_bounds__(256) void cast_all(const float* __restrict__ q, bf16* __restrict__ dq,
                                                const float* __restrict__ k, bf16* __restrict__ dk,
                                                const float* __restrict__ v, bf16* __restrict__ dv,
                                                const float* __restrict__ w0, bf16* __restrict__ e0,
                                                const float* __restrict__ w1, bf16* __restrict__ e1,
                                                const float* __restrict__ w2, bf16* __restrict__ e2,
                                                const float* __restrict__ w3, bf16* __restrict__ e3) {
    long i = blockIdx.x * 256 + threadIdx.x;  // f32x4 index
    const float* s;
    bf16* d;
    if (blockIdx.y < 3) {
        s = blockIdx.y == 0 ? q : (blockIdx.y == 1 ? k : v);
        d = blockIdx.y == 0 ? dq : (blockIdx.y == 1 ? dk : dv);
    } else {
        const long per = (long)(D_ * D_) / 4;  // 262144 f32x4 per weight
        long wsel = i / per;
        if (wsel >= 4) return;
        i -= wsel * per;
        s = wsel == 0 ? w0 : (wsel == 1 ? w1 : (wsel == 2 ? w2 : w3));
        d = wsel == 0 ? e0 : (wsel == 1 ? e1 : (wsel == 2 ? e2 : e3));
    }
    f32x4 val = ((const f32x4*)s)[i];
    bf16x4 o;
    o.x = (bf16)val.x; o.y = (bf16)val.y; o.z = (bf16)val.z; o.w = (bf16)val.w;
    ((bf16x4*)d)[i] = o;
}

// ---------------------------------------------------------------- NT GEMM body (dbuf)
// (exact round-6 structure -- known-good)
// C = (A * W^T + bias) * scale, M=8192 N=K=1024 hardcoded shape. 128x128 tile,
// BK=32, double-buffered LDS, next-tile global_load_lds issued BEFORE compute
// (single barrier/iter finds loads complete). XCD swizzle pins A row-slices.
// VMODE=1: coalesced transposed per-head V write via a TWO-PASS per-64-row LDS
// transpose tile (17408B, overlays As/Bs) so kernel LDS stays 32768 -> 5
// blocks/CU. Key 8-block permutation (1<->2 within each 32) baked into the V
// store so attn's permlane16_swap P-fragment matches V columns.
template <typename OutT, int VMODE>
__device__ __forceinline__ void gemm_body(const bf16* __restrict__ A,
                                          const bf16* __restrict__ W,
                                          const float* __restrict__ bias,
                                          OutT* __restrict__ C,
                                          int lin, float scale,
                                          bf16* As, bf16* Bs, bf16* Tt) {
    const int K = D_, N = D_;
    const int tid = threadIdx.x;
    const int wid = tid >> 6, lane = tid & 63;
    const int quad = lane >> 4, l15 = lane & 15;
    const int wm = (wid >> 1) * 64, wn = (wid & 1) * 64;
    const int bx = N >> 7;  // 8
    const int ty = (lin & 7) + 8 * (lin / (8 * bx));  // A-slice index (XCD-pinned)
    const int tx = (lin >> 3) % bx;                   // W-tile index (swept per XCD)
    const long rowA0 = (long)ty * 128;
    const long rowB0 = (long)tx * 128;
    const int srow = lane >> 2;
    const int schunk = (lane & 3) * 8;
    const int sbase = (wid * 32) * 32;

    f32x4 acc[4][4];
#pragma unroll
    for (int i = 0; i < 4; i++)
#pragma unroll
        for (int j = 0; j < 4; j++) acc[i][j] = (f32x4){0.f, 0.f, 0.f, 0.f};

    // prologue: stage k-tile 0 into buffer 0
#pragma unroll
    for (int s = 0; s < 2; s++) {
        int r = wid * 32 + s * 16 + srow;
        async_load16(&A[(rowA0 + r) * K + schunk], &As[sbase + s * 16 * 32]);
        async_load16(&W[(rowB0 + r) * K + schunk], &Bs[sbase + s * 16 * 32]);
    }
    __syncthreads();

    const int NIT = K >> 5;  // 32
    for (int it = 0; it < NIT; it++) {
        const int cur = it & 1;
        const int co = cur * (128 * 32);
        if (it + 1 < NIT) {
            const int k1 = (it + 1) << 5;
            const int no = (cur ^ 1) * (128 * 32);
#pragma unroll
            for (int s = 0; s < 2; s++) {
                int r = wid * 32 + s * 16 + srow;
                async_load16(&A[(rowA0 + r) * K + k1 + schunk], &As[no + sbase + s * 16 * 32]);
                async_load16(&W[(rowB0 + r) * K + k1 + schunk], &Bs[no + sbase + s * 16 * 32]);
            }
        }
        bf16x8 af[4], bfr[4];
#pragma unroll
        for (int i = 0; i < 4; i++)
            af[i] = *(const bf16x8*)&As[co + (wm + i * 16 + l15) * 32 + quad * 8];
#pragma unroll
        for (int j = 0; j < 4; j++)
            bfr[j] = *(const bf16x8*)&Bs[co + (wn + j * 16 + l15) * 32 + quad * 8];
#pragma unroll
        for (int i = 0; i < 4; i++)
#pragma unroll
            for (int j = 0; j < 4; j++)
                acc[i][j] = __builtin_amdgcn_mfma_f32_16x16x32_bf16(af[i], bfr[j],
                                                                    acc[i][j], 0, 0, 0);
        __syncthreads();  // next-tile loads (issued pre-compute) drain ~free
    }

    if constexpr (VMODE == 0) {
#pragma unroll
        for (int i = 0; i < 4; i++) {
            long m = rowA0 + wm + i * 16 + quad * 4;
#pragma unroll
            for (int j = 0; j < 4; j++) {
                long n = rowB0 + wn + j * 16 + l15;
                float bb = bias[n];
#pragma unroll
                for (int r = 0; r < 4; r++) {
                    float v = (acc[i][j][r] + bb) * scale;
                    C[(m + r) * N + n] = (OutT)v;
                }
            }
        }
    } else {
        // Two-pass transpose -> coalesced VT[(b*H+h)*64+d][t] stores.
        const long bidx = rowA0 >> 11;        // batch
        const int t0 = (int)(rowA0 & 2047);   // t within batch
#pragma unroll
        for (int p2 = 0; p2 < 2; p2++) {
            if (p2) __syncthreads();  // protect tile reuse from pass-0 reads
#pragma unroll
            for (int j2 = 0; j2 < 2; j2++) {
                int j = p2 * 2 + j2;
                int nl = wn + j * 16 + l15;
                int rr = (nl & 31) + ((nl >> 6) << 5);
                float bb = bias[rowB0 + nl];
#pragma unroll
                for (int i = 0; i < 4; i++) {
                    int ml = wm + i * 16 + quad * 4;
                    bf16x4 ov = {(bf16)(acc[i][j][0] + bb), (bf16)(acc[i][j][1] + bb),
                                 (bf16)(acc[i][j][2] + bb), (bf16)(acc[i][j][3] + bb)};
                    *(bf16x4*)&Tt[rr * 136 + ml] = ov;
                }
            }
            __syncthreads();
#pragma unroll
            for (int p = 0; p < 4; p++) {
                int idx = p * 16 + (tid >> 4);
                int c = tid & 15;
                bf16x8 val = *(const bf16x8*)&Tt[idx * 136 + c * 8];
                int n = (int)rowB0 + (idx & 31) + p2 * 32 + ((idx >> 5) << 6);
                long vrow = (bidx * H_ + (n >> 6)) * (long)HD_ + (n & 63);
                // key 8-block permutation: within each 32-key group swap blocks 1<->2
                int cp = (c & ~3) | ((c & 1) << 1) | ((c & 2) >> 1);
                *(bf16x8*)&((bf16*)C)[vrow * T_ + t0 + cp * 8] = val;
            }
        }
    }
}

// fused Q/K/V projection: 3 x 512 blocks in one launch. LDS exactly 32768
// (two-pass V epilogue overlays) -> 5 blocks/CU.
__global__ __launch_bounds__(256) void gemm_qkv(const bf16* __restrict__ Xq,
                                                const bf16* __restrict__ WqB,
                                                const float* __restrict__ bq,
                                                bf16* __restrict__ Qp,
                                                const bf16* __restrict__ Xk,
                                                const bf16* __restrict__ WkB,
                                                const float* __restrict__ bk,
                                                bf16* __restrict__ Kp,
                                                const bf16* __restrict__ Xv,
                                                const bf16* __restrict__ WvB,
                                                const float* __restrict__ bv,
                                                bf16* __restrict__ VtG) {
    __shared__ __align__(16) char sm[32768];
    bf16* As = (bf16*)sm;
    bf16* Bs = (bf16*)(sm + 16384);
    bf16* Tt = (bf16*)sm;
    const int p = blockIdx.x >> 9;
    const int lin = blockIdx.x & 511;
    if (p == 0)
        gemm_body<bf16, 0>(Xq, WqB, bq, Qp, lin, QSCALE, As, Bs, Tt);
    else if (p == 1)
        gemm_body<bf16, 0>(Xk, WkB, bk, Kp, lin, 1.f, As, Bs, Tt);
    else
        gemm_body<bf16, 1>(Xv, WvB, bv, VtG, lin, 1.f, As, Bs, Tt);
}

__global__ __launch_bounds__(256) void gemm_out(const bf16* __restrict__ Op,
                                                const bf16* __restrict__ WoB,
                                                const float* __restrict__ bo,
                                                float* __restrict__ out) {
    __shared__ __align__(16) char sm[32768];
    bf16* As = (bf16*)sm;
    bf16* Bs = (bf16*)(sm + 16384);
    gemm_body<float, 0>(Op, WoB, bo, out, blockIdx.x, 1.f, As, Bs, nullptr);
}

// ---------------------------------------------------------------- flash attention (S^T form)
// EXACT round-6 control flow / staging / barriers (known-good). Only delta:
// pat0/pat1 (the two XOR chunk patterns) and the zero accumulator z4 hoisted
// out of the loop -- pure expression-level CSE, no structural change. This is
// the minimal test of the addr-VALU theory after round 7's restructure broke
// correctness at the codegen level despite being source-equivalent.
// 512 threads = 8 waves x 16 q = 128 q/block; grid = 1024 blocks = 4 blocks/CU
// = 32 waves/CU. S^T = K*Q^T so q = MFMA col (l15). P never touches LDS.
// lsum rides the MFMA pipe via an all-ones A-fragment.
__global__ __launch_bounds__(512, 8) void attn_kernel(const bf16* __restrict__ Qp,
                                                      const bf16* __restrict__ Kp,
                                                      const bf16* __restrict__ VT,
                                                      bf16* __restrict__ Op) {
    __shared__ bf16 smem[4][64 * 64];  // [0..1]=K dbuf, [2..3]=V dbuf; epilogue scratch
    const int tid = threadIdx.x;
    const int wid = tid >> 6, lane = tid & 63;   // wid 0..7
    const int quad = lane >> 4, l15 = lane & 15;
    const int q7 = l15 & 7;
    const int lin = blockIdx.x;
    const int bh = (lin & 7) + 8 * (lin >> 7);  // XCD-pinned head (1024 blocks)
    const int qt = (lin >> 3) & 15;             // 16 q-tiles of 128, swept within XCD
    const int b = bh >> 4, h = bh & 15;
    const long tok0 = (long)b * T_ + (long)qt * 128 + wid * 16;
    const int hcol = h * HD_;
    const long vrow0 = ((long)bh) * HD_;
    const int g_sw = ((lane & 7) ^ (lane >> 3)) * 8;
    const int srow = lane >> 3;
    const int sbase = (wid * 8) * 64;  // each wave stages 8 rows of the 64-row tiles

    // preload kt=0 staging (1 K-row-block + 1 V-row-block per wave)
    {
        const long krow0 = (long)b * T_;
        const int r = wid * 8 + srow;
        async_load16(&Kp[(krow0 + r) * D_ + hcol + g_sw], &smem[0][sbase]);
        async_load16(&VT[(vrow0 + r) * T_ + g_sw], &smem[2][sbase]);
    }

    // Q B-frags (n = q = l15, k = d): persistent; Qp already scaled by 0.125*log2e
    bf16x8 bq0 = *(const bf16x8*)&Qp[(tok0 + l15) * D_ + hcol + quad * 8];
    bf16x8 bq1 = *(const bf16x8*)&Qp[(tok0 + l15) * D_ + hcol + 32 + quad * 8];

    // all-ones A-frag for the lsum MFMA; persistent zero for the S accumulator
    const u32x4 onesu = {0x3F803F80u, 0x3F803F80u, 0x3F803F80u, 0x3F803F80u};
    const bf16x8 ones = __builtin_bit_cast(bf16x8, onesu);
    const f32x4 z4 = (f32x4){0.f, 0.f, 0.f, 0.f};

    // hoisted XOR chunk patterns: serve all K/V fragment reads
    const int pat0 = (quad ^ q7) * 8;
    const int pat1 = ((4 + quad) ^ q7) * 8;

    f32x4 o[4];  // o[mt] = O^T[d=mt*16+quad*4+r][q=l15]
#pragma unroll
    for (int mt = 0; mt < 4; mt++) o[mt] = (f32x4){0.f, 0.f, 0.f, 0.f};
    f32x4 ls = z4;  // all 4 elements identical = sum_k P[k][q]

    __syncthreads();  // drain preload

    const int h0 = wid & 1;  // phase stagger (kept from r6 -- neutral, minimal diff)

    for (int kt = 0; kt < NKT; kt++) {
        const int cur = kt & 1;
        // issue NEXT tile's staging now; compute below hides its latency
        if (kt + 1 < NKT) {
            const long krow1 = (long)b * T_ + (long)(kt + 1) * 64;
            const int nb = cur ^ 1;
            const int r = wid * 8 + srow;
            async_load16(&Kp[(krow1 + r) * D_ + hcol + g_sw], &smem[nb][sbase]);
            async_load16(&VT[(vrow0 + r) * T_ + (long)(kt + 1) * 64 + g_sw],
                         &smem[2 + nb][sbase]);
        }
        const bf16* Ksc = smem[cur];
        const bf16* Vsc = smem[2 + cur];

        // one 32-key half: S^T -> exp2 -> pack -> permlane-swap -> lsum + PV
        auto half_step = [&](int hh) {
            uint32_t pA[2], pB[2];
#pragma unroll
            for (int mt = 0; mt < 2; mt++) {
                const bf16* kr = &Ksc[(hh * 32 + mt * 16 + l15) * 64];
                bf16x8 ak0 = *(const bf16x8*)&kr[pat0];
                bf16x8 ak1 = *(const bf16x8*)&kr[pat1];
                f32x4 s = __builtin_amdgcn_mfma_f32_16x16x32_bf16(ak0, bq0, z4, 0, 0, 0);
                s = __builtin_amdgcn_mfma_f32_16x16x32_bf16(ak1, bq1, s, 0, 0, 0);
                float p0 = fast_exp2(s[0]), p1 = fast_exp2(s[1]);
                float p2 = fast_exp2(s[2]), p3 = fast_exp2(s[3]);
                pA[mt] = pack2_bf16(p0, p1);
                pB[mt] = pack2_bf16(p2, p3);
            }
            permswap16(pA[0], pA[1]);
            permswap16(pB[0], pB[1]);
            u32x4 f = {pA[0], pB[0], pA[1], pB[1]};
            bf16x8 pb = __builtin_bit_cast(bf16x8, f);
            ls = __builtin_amdgcn_mfma_f32_16x16x32_bf16(ones, pb, ls, 0, 0, 0);
            const int vch = hh ? pat1 : pat0;
#pragma unroll
            for (int mt = 0; mt < 4; mt++) {
                bf16x8 av = *(const bf16x8*)&Vsc[(mt * 16 + l15) * 64 + vch];
                o[mt] = __builtin_amdgcn_mfma_f32_16x16x32_bf16(av, pb, o[mt], 0, 0, 0);
            }
        };
        half_step(h0);
        half_step(h0 ^ 1);
        __syncthreads();  // next-tile loads (issued pre-compute) drain here ~free
    }

    // ls already holds the full key-sum for q=l15 (MFMA reduced over k); no shfl needed
    const float linv = 1.f / ls[0];

    // epilogue: O^T -> [q][d] via wave-private swizzled LDS (reuse K/V buffers;
    // all waves' K/V reads finished at the loop's final barrier)
    bf16* ew = (bf16*)smem + wid * (16 * 64);
#pragma unroll
    for (int mt = 0; mt < 4; mt++) {
        bf16x4 ov = {(bf16)(o[mt][0] * linv), (bf16)(o[mt][1] * linv),
                     (bf16)(o[mt][2] * linv), (bf16)(o[mt][3] * linv)};
        *(bf16x4*)&ew[l15 * 64 + (((mt * 2 + (quad >> 1)) ^ q7) * 8) + (quad & 1) * 4] = ov;
    }
#pragma unroll
    for (int p2 = 0; p2 < 2; p2++) {
        int q = p2 * 8 + (lane >> 3);
        int dc = lane & 7;
        bf16x8 ov = *(const bf16x8*)&ew[q * 64 + ((dc ^ (q & 7)) * 8)];
        *(bf16x8*)&Op[(tok0 + q) * D_ + hcol + dc * 8] = ov;
    }
}

// ---------------------------------------------------------------- launch
extern "C" void kernel_launch(void* const* d_in, const int* in_sizes, int n_in,
                              void* d_out, int out_size, void* d_ws, size_t ws_size,
                              hipStream_t stream) {
    const float* q  = (const float*)d_in[0];
    const float* k  = (const float*)d_in[1];
    const float* v  = (const float*)d_in[2];
    const float* Wq = (const float*)d_in[3];
    const float* bq = (const float*)d_in[4];
    const float* Wk = (const float*)d_in[5];
    const float* bk = (const float*)d_in[6];
    const float* Wv = (const float*)d_in[7];
    const float* bv = (const float*)d_in[8];
    const float* Wo = (const float*)d_in[9];
    const float* bo = (const float*)d_in[10];
    float* out = (float*)d_out;

    const size_t MD = (size_t)B_ * T_ * D_;  // 8388608
    const size_t DD = (size_t)D_ * D_;
    char* ws = (char*)d_ws;
    bf16* Xq  = (bf16*)ws; ws += MD * 2;
    bf16* Xk  = (bf16*)ws; ws += MD * 2;
    bf16* Xv  = (bf16*)ws; ws += MD * 2;
    bf16* WqB = (bf16*)ws; ws += DD * 2;
    bf16* WkB = (bf16*)ws; ws += DD * 2;
    bf16* WvB = (bf16*)ws; ws += DD * 2;
    bf16* WoB = (bf16*)ws; ws += DD * 2;
    bf16* Qp  = (bf16*)ws; ws += MD * 2;
    bf16* Kp  = (bf16*)ws; ws += MD * 2;
    bf16* VtG = (bf16*)ws; ws += MD * 2;
    bf16* Op  = (bf16*)ws; ws += MD * 2;

    cast_all<<<dim3(MD / 4 / 256, 4), 256, 0, stream>>>(q, Xq, k, Xk, v, Xv,
                                                        Wq, WqB, Wk, WkB, Wv, WvB, Wo, WoB);

    gemm_qkv<<<3 * 512, 256, 0, stream>>>(Xq, WqB, bq, Qp, Xk, WkB, bk, Kp, Xv, WvB, bv, VtG);

    attn_kernel<<<B_ * H_ * (T_ / 128), 512, 0, stream>>>(Qp, Kp, VtG, Op);

    gemm_out<<<512, 256, 0, stream>>>(Op, WoB, bo, out);
}